// Round 2
// baseline (6678.793 us; speedup 1.0000x reference)
//
#include <hip/hip_runtime.h>
#include <hip/hip_bf16.h>

// Persistent fused kernel, v3: 256 blocks x 1024 threads (16 waves, 4/SIMD).
// v2 post-mortem: occupancy fixed (48%) but per-CU weight ingest stuck at
// ~35 GB/s because register-direct loads cap in-flight bytes at the VGPR
// budget (~15 x 16B/wave at 260cy L2 latency). v3 streams every MFMA
// B-fragment via global_load_lds (per-lane gathered global addrs ->
// lane-linear LDS dest) into a per-wave 6-slot ring with counted
// s_waitcnt vmcnt(N) -- in-flight depth now lives in LDS (96KB/block),
// not VGPRs. Target: per-CU L1<->L2 link (~64B/cy) => ~13.4us/step.
//
// DTYPE-AGNOSTIC: probe classifies bn_var bit pattern; bf16-native and fp32
// variants both launch, each no-ops unless the flag matches. fp32 mode
// pre-converts weights to bf16 in d_ws when it fits (staged path requires
// bf16 weights; the no-ws fallback keeps the register path).

typedef unsigned short u16;
typedef __attribute__((ext_vector_type(8))) short short8;
typedef __attribute__((ext_vector_type(4))) float f32x4;
typedef __bf16 bf16x8 __attribute__((ext_vector_type(8)));

#define TDIM 64
#define HDIM 512
#define ODIM 256
#define RROWS 16
#define NBLK 256
#define NTHR 1024     // 16 waves -> 4 waves/SIMD, 1 block/CU
#define PITCH 520     // 512+8: breaks ds_read_b128 bank aliasing
#define PITCH_O 264   // 256+8
#define SLOTS 6       // staging ring slots per wave (1KB each)
#define STW (SLOTS*512)

// ws layout (u16 elems, after 64-byte flag header)
#define WS_LINW   0u
#define WS_DECWIH 131072u
#define WS_OUTW   917504u
#define WS_PREWIH 1048576u
#define WS_DECWHH 1835008u
#define WS_TOTAL  2621440u

__device__ inline float b2f(u16 u) {
    unsigned v = ((unsigned)u) << 16;
    float f; __builtin_memcpy(&f, &v, 4); return f;
}
__device__ inline u16 f2b(float f) {   // RNE
    unsigned u; __builtin_memcpy(&u, &f, 4);
    return (u16)((u + 0x7fffu + ((u >> 16) & 1u)) >> 16);
}
__device__ inline float sigm(float x) {
    return __builtin_amdgcn_rcpf(1.f + __expf(-x));
}
__device__ inline float tanh_f(float x) {
    return 1.f - 2.f * __builtin_amdgcn_rcpf(1.f + __expf(2.f * x));
}
__device__ inline f32x4 mfma16(short8 a, short8 b, f32x4 c) {
    return __builtin_amdgcn_mfma_f32_16x16x32_bf16(
        __builtin_bit_cast(bf16x8, a), __builtin_bit_cast(bf16x8, b), c, 0, 0, 0);
}
// one MFMA B-fragment: 64 lanes x 16B, per-lane global src, lane-linear LDS dst
__device__ inline void gld16(const u16* g, u16* l) {
    __builtin_amdgcn_global_load_lds(
        (const __attribute__((address_space(1))) void*)g,
        (__attribute__((address_space(3))) void*)l, 16, 0, 0);
}
template<int N> __device__ inline void waitvm() {
    asm volatile("s_waitcnt vmcnt(%0)" :: "n"(N) : "memory");
}

template<int WF32> __device__ inline short8 ldw8(const void* p, size_t off) {
    if constexpr (!WF32) {
        return *(const short8*)((const u16*)p + off);
    } else {
        const float* f = (const float*)p + off;
        f32x4 a = *(const f32x4*)f, b = *(const f32x4*)(f + 4);
        short8 r;
        r[0] = (short)f2b(a[0]); r[1] = (short)f2b(a[1]);
        r[2] = (short)f2b(a[2]); r[3] = (short)f2b(a[3]);
        r[4] = (short)f2b(b[0]); r[5] = (short)f2b(b[1]);
        r[6] = (short)f2b(b[2]); r[7] = (short)f2b(b[3]);
        return r;
    }
}
template<int IOF32> __device__ inline float ldf(const void* p, int i) {
    if constexpr (IOF32) return ((const float*)p)[i];
    else return b2f(((const u16*)p)[i]);
}

// ---- probe: bn_var in [0.5,1.5]. bf16 buffer -> all u16s match the
// 0x3F00/0x3F80 pattern; fp32 buffer -> only the 8 high-halves do. ----
__global__ void probe_k(const u16* __restrict__ bnv, int* __restrict__ flag) {
    if (threadIdx.x == 0 && blockIdx.x == 0) {
        int hits = 0;
        for (int i = 0; i < 16; ++i) {
            u16 m = (u16)(bnv[i] & 0xFF80u);
            hits += (m == 0x3F00u || m == 0x3F80u) ? 1 : 0;
        }
        *flag = (hits >= 14) ? 1 : 0;   // 1 = bf16 inputs, 0 = fp32 inputs
    }
}

// ---- fp32 mode: round weights to bf16 into ws (runs only when flag==0) ----
__global__ void cvtw_k(const int* __restrict__ flag,
                       const float* __restrict__ linW,
                       const float* __restrict__ decWih,
                       const float* __restrict__ outW,
                       const float* __restrict__ preWih,
                       const float* __restrict__ decWhh,
                       u16* __restrict__ dst) {
    if (*flag == 1) return;
    int i = blockIdx.x * blockDim.x + threadIdx.x;
    const int st = gridDim.x * blockDim.x;
    for (; i < (int)WS_TOTAL; i += st) {
        int j = i; const float* s;
        if (j < 131072) s = linW + j;
        else if ((j -= 131072) < 786432) s = decWih + j;
        else if ((j -= 786432) < 131072) s = outW + j;
        else if ((j -= 131072) < 786432) s = preWih + j;
        else { j -= 786432; s = decWhh + j; }
        dst[i] = f2b(*s);
    }
}

// WF32: weight pointers are fp32 (convert per-fragment, register path).
// IOF32: biases/emb read as fp32 and output written as fp32.
template<int WF32, int IOF32>
__global__ __launch_bounds__(NTHR, 4)
void c2g_kernel(const int* __restrict__ flag,
                const int* __restrict__ cluster,
                const void* __restrict__ emb,
                const void* __restrict__ preWih,
                const void* __restrict__ preBih,
                const void* __restrict__ preBhh,
                const void* __restrict__ linW,
                const void* __restrict__ linB,
                const void* __restrict__ bnG,
                const void* __restrict__ bnB,
                const void* __restrict__ bnM,
                const void* __restrict__ bnV,
                const void* __restrict__ decWih,
                const void* __restrict__ decBih,
                const void* __restrict__ decWhh,
                const void* __restrict__ decBhh,
                const void* __restrict__ outW,
                const void* __restrict__ outB,
                void* __restrict__ out)
{
    if ((*flag == 1) == (IOF32 != 0)) return;   // proceed only on dtype match

    __shared__ __align__(16) u16 x_lds[RROWS * PITCH];
    __shared__ __align__(16) u16 h_lds[RROWS * PITCH];
    __shared__ __align__(16) u16 o_lds[RROWS * PITCH_O];
    __shared__ __align__(16) u16 stage[16 * STW];   // 96KB staging rings
    // 16640*2 + 8448 + 98304 = 140,032 B -> 1 block/CU, 16 waves resident

    const int tid  = threadIdx.x;
    const int wave = tid >> 6;    // 0..15
    const int lane = tid & 63;
    const int n16  = lane & 15;   // MFMA col (feature j within 16-tile) / A-row
    const int q    = lane >> 4;   // K-quad for A/B frags; row-quad for C
    const int qo   = q * 8;
    const int le   = lane * 8;    // staged-fragment read offset (elems)
    const int blk  = blockIdx.x;
    const int r0   = blk * RROWS;
    const int swe  = wave * STW;  // wave's staging slice (uniform)
    u16* const sw  = &stage[swe];

    // ---- init: zero decoder input, zero output frame 0, gather embeddings --
    for (int i = tid; i < RROWS * PITCH_O; i += NTHR) o_lds[i] = 0;
    for (int i = tid; i < RROWS * ODIM; i += NTHR) {
        int m = i >> 8, c = i & 255;
        size_t idx = (size_t)(r0 + m) * TDIM * ODIM + c;
        if constexpr (IOF32) __builtin_nontemporal_store(0.f, (float*)out + idx);
        else                 __builtin_nontemporal_store((u16)0, (u16*)out + idx);
    }
    for (int i = tid; i < RROWS * HDIM; i += NTHR) {
        int m = i >> 9, c = i & 511;
        x_lds[m * PITCH + c] =
            f2b(ldf<IOF32>(emb, cluster[r0 + m] * HDIM + c));
    }
    __syncthreads();

    const int jc0 = (wave * 2 + 0) * 16 + n16;
    const int jc1 = (wave * 2 + 1) * 16 + n16;
    const int jc3 = wave * 16 + n16;            // G3 column (0..255)

    // =====================================================================
    // Encoder GRU (h0 = 0 -> hh-gates are just pre_b_hh). enc_h -> h_lds
    // (A-operand home for the gh matmul) + ehr registers (decoder G2 use).
    // =====================================================================
    f32x4 ehr[2];
    if constexpr (WF32 == 0) {
        // staged: 6 streams (i,gate) x 16 kc, slot == stream
        const u16* wp = (const u16*)preWih;
        const u16* pe[6];
        #pragma unroll
        for (int i = 0; i < 2; ++i)
            #pragma unroll
            for (int g = 0; g < 3; ++g)
                pe[i*3+g] = wp + (size_t)(g*512 + (i ? jc1 : jc0)) * HDIM + qo;
        #pragma unroll
        for (int g = 0; g < 6; ++g) gld16(pe[g], sw + g*512);
        f32x4 acc[6];
        #pragma unroll
        for (int g = 0; g < 6; ++g) acc[g] = (f32x4){0,0,0,0};
        #pragma unroll
        for (int kc = 0; kc < 16; ++kc) {
            short8 fA = *(const short8*)&x_lds[n16 * PITCH + kc*32 + qo];
            if (kc == 15) waitvm<0>();
            #pragma unroll
            for (int g = 0; g < 6; ++g) {
                if (kc < 15) {
                    waitvm<5>();
                    short8 b = *(const short8*)&stage[swe + g*512 + le];
                    gld16(pe[g] + (kc+1)*32, sw + g*512);
                    acc[g] = mfma16(fA, b, acc[g]);
                } else {
                    short8 b = *(const short8*)&stage[swe + g*512 + le];
                    acc[g] = mfma16(fA, b, acc[g]);
                }
            }
        }
        #pragma unroll
        for (int i = 0; i < 2; ++i) {
            const int jc = i ? jc1 : jc0;
            const float bir = ldf<IOF32>(preBih, jc);
            const float biz = ldf<IOF32>(preBih, 512 + jc);
            const float bin = ldf<IOF32>(preBih, 1024 + jc);
            const float ghr = ldf<IOF32>(preBhh, jc);
            const float ghz = ldf<IOF32>(preBhh, 512 + jc);
            const float ghn = ldf<IOF32>(preBhh, 1024 + jc);
            #pragma unroll
            for (int r = 0; r < 4; ++r) {
                float rr = sigm(acc[i*3+0][r] + bir + ghr);
                float zz = sigm(acc[i*3+1][r] + biz + ghz);
                float nn = tanh_f(acc[i*3+2][r] + bin + rr * ghn);
                float ev = (1.f - zz) * nn;
                ehr[i][r] = ev;
                h_lds[(q*4+r) * PITCH + jc] = f2b(ev);
            }
        }
    } else {
        #pragma unroll
        for (int i = 0; i < 2; ++i) {
            const int jc = i ? jc1 : jc0;
            f32x4 ar = {0,0,0,0}, az = {0,0,0,0}, an = {0,0,0,0};
            #pragma unroll 4
            for (int kc = 0; kc < 16; ++kc) {
                const int ko = kc*32 + qo;
                short8 a0 = *(const short8*)&x_lds[n16 * PITCH + ko];
                short8 br = ldw8<WF32>(preWih, (size_t)(jc)        * HDIM + ko);
                short8 bz = ldw8<WF32>(preWih, (size_t)(512 + jc)  * HDIM + ko);
                short8 bn = ldw8<WF32>(preWih, (size_t)(1024 + jc) * HDIM + ko);
                ar = mfma16(a0, br, ar); az = mfma16(a0, bz, az); an = mfma16(a0, bn, an);
            }
            const float bir = ldf<IOF32>(preBih, jc);
            const float biz = ldf<IOF32>(preBih, 512 + jc);
            const float bin = ldf<IOF32>(preBih, 1024 + jc);
            const float ghr = ldf<IOF32>(preBhh, jc);
            const float ghz = ldf<IOF32>(preBhh, 512 + jc);
            const float ghn = ldf<IOF32>(preBhh, 1024 + jc);
            #pragma unroll
            for (int r = 0; r < 4; ++r) {
                float rr = sigm(ar[r] + bir + ghr);
                float zz = sigm(az[r] + biz + ghz);
                float nn = tanh_f(an[r] + bin + rr * ghn);
                float ev = (1.f - zz) * nn;
                ehr[i][r] = ev;
                h_lds[(q*4+r) * PITCH + jc] = f2b(ev);
            }
        }
    }
    __syncthreads();

    // =====================================================================
    // gh = enc_h @ dec_W_hh^T + dec_b_hh (+ dec_b_ih folded for r,z)
    // =====================================================================
    f32x4 gh[2][3];
    if constexpr (WF32 == 0) {
        const u16* wp = (const u16*)decWhh;
        const u16* ph[6];
        #pragma unroll
        for (int i = 0; i < 2; ++i)
            #pragma unroll
            for (int g = 0; g < 3; ++g)
                ph[i*3+g] = wp + (size_t)(g*512 + (i ? jc1 : jc0)) * HDIM + qo;
        #pragma unroll
        for (int g = 0; g < 6; ++g) gld16(ph[g], sw + g*512);
        f32x4 acc[6];
        #pragma unroll
        for (int g = 0; g < 6; ++g) acc[g] = (f32x4){0,0,0,0};
        #pragma unroll
        for (int kc = 0; kc < 16; ++kc) {
            short8 fA = *(const short8*)&h_lds[n16 * PITCH + kc*32 + qo];
            if (kc == 15) waitvm<0>();
            #pragma unroll
            for (int g = 0; g < 6; ++g) {
                if (kc < 15) {
                    waitvm<5>();
                    short8 b = *(const short8*)&stage[swe + g*512 + le];
                    gld16(ph[g] + (kc+1)*32, sw + g*512);
                    acc[g] = mfma16(fA, b, acc[g]);
                } else {
                    short8 b = *(const short8*)&stage[swe + g*512 + le];
                    acc[g] = mfma16(fA, b, acc[g]);
                }
            }
        }
        #pragma unroll
        for (int i = 0; i < 2; ++i) {
            const int jc = i ? jc1 : jc0;
            const float cr = ldf<IOF32>(decBhh, jc)       + ldf<IOF32>(decBih, jc);
            const float cz = ldf<IOF32>(decBhh, 512 + jc) + ldf<IOF32>(decBih, 512 + jc);
            const float cn = ldf<IOF32>(decBhh, 1024 + jc);
            #pragma unroll
            for (int r = 0; r < 4; ++r) {
                gh[i][0][r] = acc[i*3+0][r] + cr;
                gh[i][1][r] = acc[i*3+1][r] + cz;
                gh[i][2][r] = acc[i*3+2][r] + cn;
            }
        }
    } else {
        #pragma unroll
        for (int i = 0; i < 2; ++i) {
            const int jc = i ? jc1 : jc0;
            f32x4 ar = {0,0,0,0}, az = {0,0,0,0}, an = {0,0,0,0};
            #pragma unroll 4
            for (int kc = 0; kc < 16; ++kc) {
                const int ko = kc*32 + qo;
                short8 a0 = *(const short8*)&h_lds[n16 * PITCH + ko];
                short8 br = ldw8<WF32>(decWhh, (size_t)(jc)        * HDIM + ko);
                short8 bz = ldw8<WF32>(decWhh, (size_t)(512 + jc)  * HDIM + ko);
                short8 bn = ldw8<WF32>(decWhh, (size_t)(1024 + jc) * HDIM + ko);
                ar = mfma16(a0, br, ar); az = mfma16(a0, bz, az); an = mfma16(a0, bn, an);
            }
            const float cr = ldf<IOF32>(decBhh, jc)       + ldf<IOF32>(decBih, jc);
            const float cz = ldf<IOF32>(decBhh, 512 + jc) + ldf<IOF32>(decBih, 512 + jc);
            const float cn = ldf<IOF32>(decBhh, 1024 + jc);
            #pragma unroll
            for (int r = 0; r < 4; ++r) {
                gh[i][0][r] = ar[r] + cr;
                gh[i][1][r] = az[r] + cz;
                gh[i][2][r] = an[r] + cn;
            }
        }
    }

    // ---- hoisted loop-invariant scalars ----
    float c_s[2], c_o[2], c_bin[2];
    #pragma unroll
    for (int i = 0; i < 2; ++i) {
        const int jc = i ? jc1 : jc0;
        const float s = ldf<IOF32>(bnG, jc) *
            __builtin_amdgcn_rcpf(sqrtf(ldf<IOF32>(bnV, jc) + 1e-5f));
        c_s[i] = s;
        c_o[i] = (ldf<IOF32>(linB, jc) - ldf<IOF32>(bnM, jc)) * s
               + ldf<IOF32>(bnB, jc);
        c_bin[i] = ldf<IOF32>(decBih, 1024 + jc);
    }
    const float c_ob = ldf<IOF32>(outB, jc3);
    __syncthreads();

    // =====================================================================
    // 63 decoder steps
    // =====================================================================
    if constexpr (WF32 == 0) {
        const u16* lw  = (const u16*)linW;
        const u16* wih = (const u16*)decWih;
        const u16* ow  = (const u16*)outW;
        const u16* pl0 = lw + (size_t)jc0 * ODIM + qo;
        const u16* pl1 = lw + (size_t)jc1 * ODIM + qo;
        const u16* pw[6];
        #pragma unroll
        for (int i = 0; i < 2; ++i)
            #pragma unroll
            for (int g = 0; g < 3; ++g)
                pw[i*3+g] = wih + (size_t)(g*512 + (i ? jc1 : jc0)) * HDIM + qo;
        const u16* po = ow + (size_t)jc3 * HDIM + qo;

        for (int t = 0; t < TDIM - 1; ++t) {
            // ---- G1: x = relu(bn(o @ lin_W^T + lin_b)), K=256 ----
            // streams i=0,1 in slots {0..2},{3..5}, 3-deep
            #pragma unroll
            for (int kc = 0; kc < 3; ++kc) {
                gld16(pl0 + kc*32, sw + kc*512);
                gld16(pl1 + kc*32, sw + (3+kc)*512);
            }
            f32x4 a0 = {0,0,0,0}, a1 = {0,0,0,0};
            #pragma unroll
            for (int kc = 0; kc < 8; ++kc) {
                short8 fA = *(const short8*)&o_lds[n16 * PITCH_O + kc*32 + qo];
                if (kc < 5) {
                    waitvm<5>();
                    short8 w0 = *(const short8*)&stage[swe + (kc%3)*512 + le];
                    gld16(pl0 + (kc+3)*32, sw + (kc%3)*512);
                    a0 = mfma16(fA, w0, a0);
                    waitvm<5>();
                    short8 w1 = *(const short8*)&stage[swe + (3+kc%3)*512 + le];
                    gld16(pl1 + (kc+3)*32, sw + (3+kc%3)*512);
                    a1 = mfma16(fA, w1, a1);
                } else {
                    if (kc == 5) waitvm<0>();
                    short8 w0 = *(const short8*)&stage[swe + (kc%3)*512 + le];
                    a0 = mfma16(fA, w0, a0);
                    short8 w1 = *(const short8*)&stage[swe + (3+kc%3)*512 + le];
                    a1 = mfma16(fA, w1, a1);
                }
            }
            #pragma unroll
            for (int i = 0; i < 2; ++i) {
                const int jc = i ? jc1 : jc0;
                f32x4 v = i ? a1 : a0;
                #pragma unroll
                for (int r = 0; r < 4; ++r) {
                    float xv = v[r] * c_s[i] + c_o[i];
                    x_lds[(q*4+r) * PITCH + jc] = f2b(fmaxf(xv, 0.f));
                }
            }
            __syncthreads();

            // ---- G2: gi = x @ dec_W_ih^T; gates fused with gh/ehr ----
            #pragma unroll
            for (int g = 0; g < 6; ++g) gld16(pw[g], sw + g*512);
            f32x4 acc[6];
            #pragma unroll
            for (int g = 0; g < 6; ++g) acc[g] = (f32x4){0,0,0,0};
            #pragma unroll
            for (int kc = 0; kc < 16; ++kc) {
                short8 fA = *(const short8*)&x_lds[n16 * PITCH + kc*32 + qo];
                if (kc == 15) waitvm<0>();
                #pragma unroll
                for (int g = 0; g < 6; ++g) {
                    if (kc < 15) {
                        waitvm<5>();
                        short8 b = *(const short8*)&stage[swe + g*512 + le];
                        gld16(pw[g] + (kc+1)*32, sw + g*512);
                        acc[g] = mfma16(fA, b, acc[g]);
                    } else {
                        short8 b = *(const short8*)&stage[swe + g*512 + le];
                        acc[g] = mfma16(fA, b, acc[g]);
                    }
                }
            }
            #pragma unroll
            for (int i = 0; i < 2; ++i) {
                const int jc = i ? jc1 : jc0;
                #pragma unroll
                for (int r = 0; r < 4; ++r) {
                    float rr = sigm(acc[i*3+0][r] + gh[i][0][r]);
                    float zz = sigm(acc[i*3+1][r] + gh[i][1][r]);
                    float nn = tanh_f(acc[i*3+2][r] + c_bin[i] + rr * gh[i][2][r]);
                    h_lds[(q*4+r) * PITCH + jc] =
                        f2b((1.f - zz) * nn + zz * ehr[i][r]);
                }
            }
            __syncthreads();

            // ---- G3: out = h @ out_W^T + out_b, K=512 ----
            #pragma unroll
            for (int kc = 0; kc < 4; ++kc) gld16(po + kc*32, sw + kc*512);
            f32x4 a = {0,0,0,0};
            #pragma unroll
            for (int kc = 0; kc < 16; ++kc) {
                short8 fA = *(const short8*)&h_lds[n16 * PITCH + kc*32 + qo];
                if (kc < 12) {
                    waitvm<3>();
                    short8 b = *(const short8*)&stage[swe + (kc&3)*512 + le];
                    gld16(po + (kc+4)*32, sw + (kc&3)*512);
                    a = mfma16(fA, b, a);
                } else {
                    if (kc == 12) waitvm<0>();
                    short8 b = *(const short8*)&stage[swe + (kc&3)*512 + le];
                    a = mfma16(fA, b, a);
                }
            }
            #pragma unroll
            for (int r = 0; r < 4; ++r) {
                float val = a[r] + c_ob;
                int row = q*4 + r;
                o_lds[row * PITCH_O + jc3] = f2b(val);
                size_t idx = (size_t)(r0 + row) * TDIM * ODIM
                           + (size_t)(t + 1) * ODIM + jc3;
                if constexpr (IOF32)
                    __builtin_nontemporal_store(val, (float*)out + idx);
                else
                    __builtin_nontemporal_store(f2b(val), (u16*)out + idx);
            }
            __syncthreads();
        }
    } else {
        // register-path fallback (fp32 weights converted per-fragment)
        for (int t = 0; t < TDIM - 1; ++t) {
            #pragma unroll
            for (int i = 0; i < 2; ++i) {
                const int jc = i ? jc1 : jc0;
                f32x4 a = {0,0,0,0};
                #pragma unroll
                for (int kc = 0; kc < 8; ++kc) {
                    const int ko = kc*32 + qo;
                    short8 bw = ldw8<WF32>(linW, (size_t)jc * ODIM + ko);
                    short8 f0 = *(const short8*)&o_lds[n16 * PITCH_O + ko];
                    a = mfma16(f0, bw, a);
                }
                #pragma unroll
                for (int r = 0; r < 4; ++r) {
                    float xv = a[r] * c_s[i] + c_o[i];
                    x_lds[(q*4+r) * PITCH + jc] = f2b(fmaxf(xv, 0.f));
                }
            }
            __syncthreads();
            #pragma unroll
            for (int i = 0; i < 2; ++i) {
                const int jc = i ? jc1 : jc0;
                f32x4 ar = {0,0,0,0}, az = {0,0,0,0}, an = {0,0,0,0};
                #pragma unroll 4
                for (int kc = 0; kc < 16; ++kc) {
                    const int ko = kc*32 + qo;
                    short8 a0 = *(const short8*)&x_lds[n16 * PITCH + ko];
                    short8 br = ldw8<WF32>(decWih, (size_t)(jc)        * HDIM + ko);
                    short8 bz = ldw8<WF32>(decWih, (size_t)(512 + jc)  * HDIM + ko);
                    short8 bn = ldw8<WF32>(decWih, (size_t)(1024 + jc) * HDIM + ko);
                    ar = mfma16(a0, br, ar); az = mfma16(a0, bz, az); an = mfma16(a0, bn, an);
                }
                #pragma unroll
                for (int r = 0; r < 4; ++r) {
                    float rr = sigm(ar[r] + gh[i][0][r]);
                    float zz = sigm(az[r] + gh[i][1][r]);
                    float nn = tanh_f(an[r] + c_bin[i] + rr * gh[i][2][r]);
                    h_lds[(q*4+r) * PITCH + jc] =
                        f2b((1.f - zz) * nn + zz * ehr[i][r]);
                }
            }
            __syncthreads();
            {
                f32x4 a = {0,0,0,0};
                #pragma unroll 4
                for (int kc = 0; kc < 16; ++kc) {
                    const int ko = kc*32 + qo;
                    short8 bw = ldw8<WF32>(outW, (size_t)jc3 * HDIM + ko);
                    short8 f0 = *(const short8*)&h_lds[n16 * PITCH + ko];
                    a = mfma16(f0, bw, a);
                }
                #pragma unroll
                for (int r = 0; r < 4; ++r) {
                    float val = a[r] + c_ob;
                    int row = q*4 + r;
                    o_lds[row * PITCH_O + jc3] = f2b(val);
                    size_t idx = (size_t)(r0 + row) * TDIM * ODIM
                               + (size_t)(t + 1) * ODIM + jc3;
                    if constexpr (IOF32)
                        __builtin_nontemporal_store(val, (float*)out + idx);
                    else
                        __builtin_nontemporal_store(f2b(val), (u16*)out + idx);
                }
            }
            __syncthreads();
        }
    }
}

extern "C" void kernel_launch(void* const* d_in, const int* in_sizes, int n_in,
                              void* d_out, int out_size, void* d_ws, size_t ws_size,
                              hipStream_t stream) {
    const int* cluster = (const int*)d_in[0];
    // d_in[1] = out_poses: only shape matters (T frames), values unused
    // d_in[4] = pre_W_hh: dead (h0 == 0)
    int* flag = (int*)d_ws;
    u16* wsW  = (u16*)((char*)d_ws + 64);
    const size_t NEED = 64 + (size_t)WS_TOTAL * 2;

    probe_k<<<dim3(1), dim3(64), 0, stream>>>((const u16*)d_in[12], flag);

    // bf16-native variant (no-ops unless flag==1)
    c2g_kernel<0, 0><<<dim3(NBLK), dim3(NTHR), 0, stream>>>(
        flag, cluster, d_in[2], d_in[3], d_in[5], d_in[6], d_in[7], d_in[8],
        d_in[9], d_in[10], d_in[11], d_in[12], d_in[13], d_in[15], d_in[14],
        d_in[16], d_in[17], d_in[18], d_out);

    if (ws_size >= NEED) {
        // fp32 mode with pre-converted bf16 weights in ws
        cvtw_k<<<dim3(2048), dim3(256), 0, stream>>>(
            flag, (const float*)d_in[7], (const float*)d_in[13],
            (const float*)d_in[17], (const float*)d_in[3],
            (const float*)d_in[14], wsW);
        c2g_kernel<0, 1><<<dim3(NBLK), dim3(NTHR), 0, stream>>>(
            flag, cluster, d_in[2], wsW + WS_PREWIH, d_in[5], d_in[6],
            wsW + WS_LINW, d_in[8], d_in[9], d_in[10], d_in[11], d_in[12],
            wsW + WS_DECWIH, d_in[15], wsW + WS_DECWHH, d_in[16],
            wsW + WS_OUTW, d_in[18], d_out);
    } else {
        // fp32 mode, convert weights per-fragment on the fly
        c2g_kernel<1, 1><<<dim3(NBLK), dim3(NTHR), 0, stream>>>(
            flag, cluster, d_in[2], d_in[3], d_in[5], d_in[6], d_in[7], d_in[8],
            d_in[9], d_in[10], d_in[11], d_in[12], d_in[13], d_in[15], d_in[14],
            d_in[16], d_in[17], d_in[18], d_out);
    }
}

// Round 3
// 4781.969 us; speedup vs baseline: 1.3967x; 1.3967x over previous
//
#include <hip/hip_runtime.h>
#include <hip/hip_bf16.h>

// Persistent fused kernel, v4: 256 blocks x 1024 threads (16 waves, 4/SIMD).
// v3 post-mortem: global_load_lds staging of gathered B-fragments REGRESSED
// (FETCH 4x: the 16-row x 1024B-stride gather doesn't coalesce as LDS-DMA).
// v2 post-mortem arithmetic: 142K cy/step == 128 weight loads x ~1100cy fully
// serialized; VGPR_Count=64 shows the compiler had no room to double-buffer.
// v4 = v2 structure + explicit 1-ahead register rings per weight stream +
// cross-phase prefetch + raw s_barrier (lgkmcnt-only, no vmcnt drain) so
// prefetched fragments stay in flight across barriers (guide T3/T4 idiom).
//
// DTYPE-AGNOSTIC: probe classifies bn_var bit pattern; bf16-native and fp32
// variants both launch, each no-ops unless the flag matches. fp32 mode
// pre-converts weights to bf16 in d_ws when it fits.

typedef unsigned short u16;
typedef __attribute__((ext_vector_type(8))) short short8;
typedef __attribute__((ext_vector_type(4))) float f32x4;
typedef __bf16 bf16x8 __attribute__((ext_vector_type(8)));

#define TDIM 64
#define HDIM 512
#define ODIM 256
#define RROWS 16
#define NBLK 256
#define NTHR 1024     // 16 waves -> 4 waves/SIMD, 1 block/CU
#define PITCH 520     // 512+8: breaks ds_read_b128 bank aliasing
#define PITCH_O 264   // 256+8

// ws layout (u16 elems, after 64-byte flag header)
#define WS_LINW   0u
#define WS_DECWIH 131072u
#define WS_OUTW   917504u
#define WS_PREWIH 1048576u
#define WS_DECWHH 1835008u
#define WS_TOTAL  2621440u

__device__ inline float b2f(u16 u) {
    unsigned v = ((unsigned)u) << 16;
    float f; __builtin_memcpy(&f, &v, 4); return f;
}
__device__ inline u16 f2b(float f) {   // RNE
    unsigned u; __builtin_memcpy(&u, &f, 4);
    return (u16)((u + 0x7fffu + ((u >> 16) & 1u)) >> 16);
}
__device__ inline float sigm(float x) {
    return __builtin_amdgcn_rcpf(1.f + __expf(-x));
}
__device__ inline float tanh_f(float x) {
    return 1.f - 2.f * __builtin_amdgcn_rcpf(1.f + __expf(2.f * x));
}
__device__ inline f32x4 mfma16(short8 a, short8 b, f32x4 c) {
    return __builtin_amdgcn_mfma_f32_16x16x32_bf16(
        __builtin_bit_cast(bf16x8, a), __builtin_bit_cast(bf16x8, b), c, 0, 0, 0);
}
// barrier WITHOUT vmcnt drain: LDS writes must land (lgkmcnt 0), but global
// prefetch loads stay in flight across it. Memory clobbers pin LDS op order.
__device__ inline void bar_nd() {
    asm volatile("s_waitcnt lgkmcnt(0)" ::: "memory");
    __builtin_amdgcn_s_barrier();
    asm volatile("" ::: "memory");
}

template<int WF32> __device__ inline short8 ldw8(const void* p, size_t off) {
    if constexpr (!WF32) {
        return *(const short8*)((const u16*)p + off);
    } else {
        const float* f = (const float*)p + off;
        f32x4 a = *(const f32x4*)f, b = *(const f32x4*)(f + 4);
        short8 r;
        r[0] = (short)f2b(a[0]); r[1] = (short)f2b(a[1]);
        r[2] = (short)f2b(a[2]); r[3] = (short)f2b(a[3]);
        r[4] = (short)f2b(b[0]); r[5] = (short)f2b(b[1]);
        r[6] = (short)f2b(b[2]); r[7] = (short)f2b(b[3]);
        return r;
    }
}
template<int IOF32> __device__ inline float ldf(const void* p, int i) {
    if constexpr (IOF32) return ((const float*)p)[i];
    else return b2f(((const u16*)p)[i]);
}

// ---- probe: bn_var in [0.5,1.5]. bf16 buffer -> all u16s match the
// 0x3F00/0x3F80 pattern; fp32 buffer -> only the 8 high-halves do. ----
__global__ void probe_k(const u16* __restrict__ bnv, int* __restrict__ flag) {
    if (threadIdx.x == 0 && blockIdx.x == 0) {
        int hits = 0;
        for (int i = 0; i < 16; ++i) {
            u16 m = (u16)(bnv[i] & 0xFF80u);
            hits += (m == 0x3F00u || m == 0x3F80u) ? 1 : 0;
        }
        *flag = (hits >= 14) ? 1 : 0;   // 1 = bf16 inputs, 0 = fp32 inputs
    }
}

// ---- fp32 mode: round weights to bf16 into ws (runs only when flag==0) ----
__global__ void cvtw_k(const int* __restrict__ flag,
                       const float* __restrict__ linW,
                       const float* __restrict__ decWih,
                       const float* __restrict__ outW,
                       const float* __restrict__ preWih,
                       const float* __restrict__ decWhh,
                       u16* __restrict__ dst) {
    if (*flag == 1) return;
    int i = blockIdx.x * blockDim.x + threadIdx.x;
    const int st = gridDim.x * blockDim.x;
    for (; i < (int)WS_TOTAL; i += st) {
        int j = i; const float* s;
        if (j < 131072) s = linW + j;
        else if ((j -= 131072) < 786432) s = decWih + j;
        else if ((j -= 786432) < 131072) s = outW + j;
        else if ((j -= 131072) < 786432) s = preWih + j;
        else { j -= 786432; s = decWhh + j; }
        dst[i] = f2b(*s);
    }
}

// WF32: weight pointers are fp32 (convert per-fragment, unpipelined path).
// IOF32: biases/emb read as fp32 and output written as fp32.
template<int WF32, int IOF32>
__global__ __launch_bounds__(NTHR, 4)
void c2g_kernel(const int* __restrict__ flag,
                const int* __restrict__ cluster,
                const void* __restrict__ emb,
                const void* __restrict__ preWih,
                const void* __restrict__ preBih,
                const void* __restrict__ preBhh,
                const void* __restrict__ linW,
                const void* __restrict__ linB,
                const void* __restrict__ bnG,
                const void* __restrict__ bnB,
                const void* __restrict__ bnM,
                const void* __restrict__ bnV,
                const void* __restrict__ decWih,
                const void* __restrict__ decBih,
                const void* __restrict__ decWhh,
                const void* __restrict__ decBhh,
                const void* __restrict__ outW,
                const void* __restrict__ outB,
                void* __restrict__ out)
{
    if ((*flag == 1) == (IOF32 != 0)) return;   // proceed only on dtype match

    __shared__ __align__(16) u16 x_lds[RROWS * PITCH];
    __shared__ __align__(16) u16 h_lds[RROWS * PITCH];
    __shared__ __align__(16) u16 o_lds[RROWS * PITCH_O];
    // 16640*2 + 8448 = 41,728 B -> 1 block/CU, 16 waves resident

    const int tid  = threadIdx.x;
    const int wave = tid >> 6;    // 0..15
    const int lane = tid & 63;
    const int n16  = lane & 15;   // MFMA col (feature j within 16-tile) / A-row
    const int q    = lane >> 4;   // K-quad for A/B frags; row-quad for C
    const int qo   = q * 8;
    const int blk  = blockIdx.x;
    const int r0   = blk * RROWS;

    // ---- init: zero decoder input, zero output frame 0, gather embeddings --
    for (int i = tid; i < RROWS * PITCH_O; i += NTHR) o_lds[i] = 0;
    for (int i = tid; i < RROWS * ODIM; i += NTHR) {
        int m = i >> 8, c = i & 255;
        size_t idx = (size_t)(r0 + m) * TDIM * ODIM + c;
        if constexpr (IOF32) ((float*)out)[idx] = 0.f;
        else                 ((u16*)out)[idx] = 0;
    }
    for (int i = tid; i < RROWS * HDIM; i += NTHR) {
        int m = i >> 9, c = i & 511;
        x_lds[m * PITCH + c] =
            f2b(ldf<IOF32>(emb, cluster[r0 + m] * HDIM + c));
    }
    __syncthreads();

    const int jc0 = (wave * 2 + 0) * 16 + n16;
    const int jc1 = (wave * 2 + 1) * 16 + n16;
    const int jc3 = wave * 16 + n16;            // G3 column (0..255)

    // ---- encoder GRU (h0 = 0 -> hh-gates are just pre_b_hh) ----
    // enc_h -> h_lds (A-operand for the gh matmul) + ehr regs (G2 use).
    f32x4 ehr[2];
    #pragma unroll
    for (int i = 0; i < 2; ++i) {
        const int jc = i ? jc1 : jc0;
        f32x4 ar = {0,0,0,0}, az = {0,0,0,0}, an = {0,0,0,0};
        #pragma unroll 4
        for (int kc = 0; kc < 16; ++kc) {
            const int ko = kc*32 + qo;
            short8 a0 = *(const short8*)&x_lds[n16 * PITCH + ko];
            short8 br = ldw8<WF32>(preWih, (size_t)(jc)        * HDIM + ko);
            short8 bz = ldw8<WF32>(preWih, (size_t)(512 + jc)  * HDIM + ko);
            short8 bn = ldw8<WF32>(preWih, (size_t)(1024 + jc) * HDIM + ko);
            ar = mfma16(a0, br, ar); az = mfma16(a0, bz, az); an = mfma16(a0, bn, an);
        }
        const float bir = ldf<IOF32>(preBih, jc);
        const float biz = ldf<IOF32>(preBih, 512 + jc);
        const float bin = ldf<IOF32>(preBih, 1024 + jc);
        const float ghr = ldf<IOF32>(preBhh, jc);
        const float ghz = ldf<IOF32>(preBhh, 512 + jc);
        const float ghn = ldf<IOF32>(preBhh, 1024 + jc);
        #pragma unroll
        for (int r = 0; r < 4; ++r) {
            float rr = sigm(ar[r] + bir + ghr);
            float zz = sigm(az[r] + biz + ghz);
            float nn = tanh_f(an[r] + bin + rr * ghn);
            float ev = (1.f - zz) * nn;
            ehr[i][r] = ev;
            h_lds[(q*4+r) * PITCH + jc] = f2b(ev);
        }
    }
    __syncthreads();

    // ---- gh = enc_h @ dec_W_hh^T + dec_b_hh (+ dec_b_ih folded for r,z) ----
    f32x4 gh[2][3];
    #pragma unroll
    for (int i = 0; i < 2; ++i) {
        const int jc = i ? jc1 : jc0;
        f32x4 ar = {0,0,0,0}, az = {0,0,0,0}, an = {0,0,0,0};
        #pragma unroll 4
        for (int kc = 0; kc < 16; ++kc) {
            const int ko = kc*32 + qo;
            short8 a0 = *(const short8*)&h_lds[n16 * PITCH + ko];
            short8 br = ldw8<WF32>(decWhh, (size_t)(jc)        * HDIM + ko);
            short8 bz = ldw8<WF32>(decWhh, (size_t)(512 + jc)  * HDIM + ko);
            short8 bn = ldw8<WF32>(decWhh, (size_t)(1024 + jc) * HDIM + ko);
            ar = mfma16(a0, br, ar); az = mfma16(a0, bz, az); an = mfma16(a0, bn, an);
        }
        const float cr = ldf<IOF32>(decBhh, jc)       + ldf<IOF32>(decBih, jc);
        const float cz = ldf<IOF32>(decBhh, 512 + jc) + ldf<IOF32>(decBih, 512 + jc);
        const float cn = ldf<IOF32>(decBhh, 1024 + jc);
        #pragma unroll
        for (int r = 0; r < 4; ++r) {
            gh[i][0][r] = ar[r] + cr;
            gh[i][1][r] = az[r] + cz;
            gh[i][2][r] = an[r] + cn;
        }
    }

    // ---- hoisted loop-invariant scalars ----
    float c_s[2], c_o[2], c_bin[2];
    #pragma unroll
    for (int i = 0; i < 2; ++i) {
        const int jc = i ? jc1 : jc0;
        const float s = ldf<IOF32>(bnG, jc) *
            __builtin_amdgcn_rcpf(sqrtf(ldf<IOF32>(bnV, jc) + 1e-5f));
        c_s[i] = s;
        c_o[i] = (ldf<IOF32>(linB, jc) - ldf<IOF32>(bnM, jc)) * s
               + ldf<IOF32>(bnB, jc);
        c_bin[i] = ldf<IOF32>(decBih, 1024 + jc);
    }
    const float c_ob = ldf<IOF32>(outB, jc3);
    __syncthreads();

    // =====================================================================
    // 63 decoder steps
    // =====================================================================
    if constexpr (WF32 == 0) {
        const u16* lw  = (const u16*)linW;
        const u16* wih = (const u16*)decWih;
        const u16* ow  = (const u16*)outW;
        const unsigned ol0 = (unsigned)jc0 * ODIM + qo;
        const unsigned ol1 = (unsigned)jc1 * ODIM + qo;
        const unsigned og0 = (unsigned)(jc0)        * HDIM + qo;
        const unsigned og1 = (unsigned)(512 + jc0)  * HDIM + qo;
        const unsigned og2 = (unsigned)(1024 + jc0) * HDIM + qo;
        const unsigned og3 = (unsigned)(jc1)        * HDIM + qo;
        const unsigned og4 = (unsigned)(512 + jc1)  * HDIM + qo;
        const unsigned og5 = (unsigned)(1024 + jc1) * HDIM + qo;
        const unsigned oo  = (unsigned)jc3 * HDIM + qo;

        // preload G1 kc=0 pair for t=0
        short8 g1a = *(const short8*)&lw[ol0];
        short8 g1b = *(const short8*)&lw[ol1];

        for (int t = 0; t < TDIM - 1; ++t) {
            // ---- G1: x = relu(bn(o @ lin_W^T + lin_b)), K=256, 2 streams --
            f32x4 a0 = {0,0,0,0}, a1 = {0,0,0,0};
            {
                short8 b0 = g1a, b1 = g1b;
                #pragma unroll
                for (int kc = 0; kc < 8; ++kc) {
                    short8 n0, n1;
                    if (kc < 7) {
                        n0 = *(const short8*)&lw[ol0 + (unsigned)(kc+1)*32];
                        n1 = *(const short8*)&lw[ol1 + (unsigned)(kc+1)*32];
                    }
                    short8 fA = *(const short8*)&o_lds[n16 * PITCH_O + kc*32 + qo];
                    a0 = mfma16(fA, b0, a0); a1 = mfma16(fA, b1, a1);
                    if (kc < 7) { b0 = n0; b1 = n1; }
                }
            }
            // prefetch G2 half-0 trio (stays in flight across the barrier)
            short8 p0 = *(const short8*)&wih[og0];
            short8 p1 = *(const short8*)&wih[og1];
            short8 p2 = *(const short8*)&wih[og2];
            // G1 epilogue
            #pragma unroll
            for (int r = 0; r < 4; ++r) {
                float x0 = a0[r] * c_s[0] + c_o[0];
                float x1 = a1[r] * c_s[1] + c_o[1];
                x_lds[(q*4+r) * PITCH + jc0] = f2b(fmaxf(x0, 0.f));
                x_lds[(q*4+r) * PITCH + jc1] = f2b(fmaxf(x1, 0.f));
            }
            bar_nd();

            // ---- G2 half 0: gates for jc0, 3 streams, K=512 ----
            f32x4 ar = {0,0,0,0}, az = {0,0,0,0}, an = {0,0,0,0};
            {
                short8 b0 = p0, b1 = p1, b2 = p2;
                #pragma unroll
                for (int kc = 0; kc < 16; ++kc) {
                    short8 n0, n1, n2;
                    if (kc < 15) {
                        n0 = *(const short8*)&wih[og0 + (unsigned)(kc+1)*32];
                        n1 = *(const short8*)&wih[og1 + (unsigned)(kc+1)*32];
                        n2 = *(const short8*)&wih[og2 + (unsigned)(kc+1)*32];
                    }
                    short8 fA = *(const short8*)&x_lds[n16 * PITCH + kc*32 + qo];
                    ar = mfma16(fA, b0, ar); az = mfma16(fA, b1, az); an = mfma16(fA, b2, an);
                    if (kc < 15) { b0 = n0; b1 = n1; b2 = n2; }
                }
            }
            // prefetch half-1 trio
            p0 = *(const short8*)&wih[og3];
            p1 = *(const short8*)&wih[og4];
            p2 = *(const short8*)&wih[og5];
            // half-0 epilogue (frees accs before half-1 ring peaks)
            #pragma unroll
            for (int r = 0; r < 4; ++r) {
                float rr = sigm(ar[r] + gh[0][0][r]);
                float zz = sigm(az[r] + gh[0][1][r]);
                float nn = tanh_f(an[r] + c_bin[0] + rr * gh[0][2][r]);
                h_lds[(q*4+r) * PITCH + jc0] =
                    f2b((1.f - zz) * nn + zz * ehr[0][r]);
            }

            // ---- G2 half 1: gates for jc1 ----
            ar = (f32x4){0,0,0,0}; az = (f32x4){0,0,0,0}; an = (f32x4){0,0,0,0};
            {
                short8 b0 = p0, b1 = p1, b2 = p2;
                #pragma unroll
                for (int kc = 0; kc < 16; ++kc) {
                    short8 n0, n1, n2;
                    if (kc < 15) {
                        n0 = *(const short8*)&wih[og3 + (unsigned)(kc+1)*32];
                        n1 = *(const short8*)&wih[og4 + (unsigned)(kc+1)*32];
                        n2 = *(const short8*)&wih[og5 + (unsigned)(kc+1)*32];
                    }
                    short8 fA = *(const short8*)&x_lds[n16 * PITCH + kc*32 + qo];
                    ar = mfma16(fA, b0, ar); az = mfma16(fA, b1, az); an = mfma16(fA, b2, an);
                    if (kc < 15) { b0 = n0; b1 = n1; b2 = n2; }
                }
            }
            // prefetch G3 kc=0,1
            short8 e0 = *(const short8*)&ow[oo];
            short8 e1 = *(const short8*)&ow[oo + 32];
            // half-1 epilogue
            #pragma unroll
            for (int r = 0; r < 4; ++r) {
                float rr = sigm(ar[r] + gh[1][0][r]);
                float zz = sigm(az[r] + gh[1][1][r]);
                float nn = tanh_f(an[r] + c_bin[1] + rr * gh[1][2][r]);
                h_lds[(q*4+r) * PITCH + jc1] =
                    f2b((1.f - zz) * nn + zz * ehr[1][r]);
            }
            bar_nd();

            // ---- G3: out = h @ out_W^T + out_b, K=512, distance-2 ring ----
            f32x4 a = {0,0,0,0};
            #pragma unroll
            for (int kc = 0; kc < 16; ++kc) {
                short8 nn;
                if (kc < 14)
                    nn = *(const short8*)&ow[oo + (unsigned)(kc+2)*32];
                short8 fA = *(const short8*)&h_lds[n16 * PITCH + kc*32 + qo];
                a = mfma16(fA, e0, a);
                e0 = e1;
                if (kc < 14) e1 = nn;
            }
            // prefetch next-step G1 pair (crosses the loop-end barrier)
            g1a = *(const short8*)&lw[ol0];
            g1b = *(const short8*)&lw[ol1];
            // G3 epilogue
            #pragma unroll
            for (int r = 0; r < 4; ++r) {
                float val = a[r] + c_ob;
                int row = q*4 + r;
                o_lds[row * PITCH_O + jc3] = f2b(val);
                size_t idx = (size_t)(r0 + row) * TDIM * ODIM
                           + (size_t)(t + 1) * ODIM + jc3;
                if constexpr (IOF32) ((float*)out)[idx] = val;
                else                 ((u16*)out)[idx] = f2b(val);
            }
            bar_nd();
        }
    } else {
        // fallback: fp32 weights converted per-fragment (ws too small)
        for (int t = 0; t < TDIM - 1; ++t) {
            #pragma unroll
            for (int i = 0; i < 2; ++i) {
                const int jc = i ? jc1 : jc0;
                f32x4 a = {0,0,0,0};
                #pragma unroll
                for (int kc = 0; kc < 8; ++kc) {
                    const int ko = kc*32 + qo;
                    short8 bw = ldw8<WF32>(linW, (size_t)jc * ODIM + ko);
                    short8 f0 = *(const short8*)&o_lds[n16 * PITCH_O + ko];
                    a = mfma16(f0, bw, a);
                }
                #pragma unroll
                for (int r = 0; r < 4; ++r) {
                    float xv = a[r] * c_s[i] + c_o[i];
                    x_lds[(q*4+r) * PITCH + jc] = f2b(fmaxf(xv, 0.f));
                }
            }
            __syncthreads();
            #pragma unroll
            for (int i = 0; i < 2; ++i) {
                const int jc = i ? jc1 : jc0;
                f32x4 ar = {0,0,0,0}, az = {0,0,0,0}, an = {0,0,0,0};
                #pragma unroll 4
                for (int kc = 0; kc < 16; ++kc) {
                    const int ko = kc*32 + qo;
                    short8 a0 = *(const short8*)&x_lds[n16 * PITCH + ko];
                    short8 br = ldw8<WF32>(decWih, (size_t)(jc)        * HDIM + ko);
                    short8 bz = ldw8<WF32>(decWih, (size_t)(512 + jc)  * HDIM + ko);
                    short8 bn = ldw8<WF32>(decWih, (size_t)(1024 + jc) * HDIM + ko);
                    ar = mfma16(a0, br, ar); az = mfma16(a0, bz, az); an = mfma16(a0, bn, an);
                }
                #pragma unroll
                for (int r = 0; r < 4; ++r) {
                    float rr = sigm(ar[r] + gh[i][0][r]);
                    float zz = sigm(az[r] + gh[i][1][r]);
                    float nn = tanh_f(an[r] + c_bin[i] + rr * gh[i][2][r]);
                    h_lds[(q*4+r) * PITCH + jc] =
                        f2b((1.f - zz) * nn + zz * ehr[i][r]);
                }
            }
            __syncthreads();
            {
                f32x4 a = {0,0,0,0};
                #pragma unroll 4
                for (int kc = 0; kc < 16; ++kc) {
                    const int ko = kc*32 + qo;
                    short8 bw = ldw8<WF32>(outW, (size_t)jc3 * HDIM + ko);
                    short8 f0 = *(const short8*)&h_lds[n16 * PITCH + ko];
                    a = mfma16(f0, bw, a);
                }
                #pragma unroll
                for (int r = 0; r < 4; ++r) {
                    float val = a[r] + c_ob;
                    int row = q*4 + r;
                    o_lds[row * PITCH_O + jc3] = f2b(val);
                    size_t idx = (size_t)(r0 + row) * TDIM * ODIM
                               + (size_t)(t + 1) * ODIM + jc3;
                    if constexpr (IOF32) ((float*)out)[idx] = val;
                    else                 ((u16*)out)[idx] = f2b(val);
                }
            }
            __syncthreads();
        }
    }
}

extern "C" void kernel_launch(void* const* d_in, const int* in_sizes, int n_in,
                              void* d_out, int out_size, void* d_ws, size_t ws_size,
                              hipStream_t stream) {
    const int* cluster = (const int*)d_in[0];
    // d_in[1] = out_poses: only shape matters (T frames), values unused
    // d_in[4] = pre_W_hh: dead (h0 == 0)
    int* flag = (int*)d_ws;
    u16* wsW  = (u16*)((char*)d_ws + 64);
    const size_t NEED = 64 + (size_t)WS_TOTAL * 2;

    probe_k<<<dim3(1), dim3(64), 0, stream>>>((const u16*)d_in[12], flag);

    // bf16-native variant (no-ops unless flag==1)
    c2g_kernel<0, 0><<<dim3(NBLK), dim3(NTHR), 0, stream>>>(
        flag, cluster, d_in[2], d_in[3], d_in[5], d_in[6], d_in[7], d_in[8],
        d_in[9], d_in[10], d_in[11], d_in[12], d_in[13], d_in[15], d_in[14],
        d_in[16], d_in[17], d_in[18], d_out);

    if (ws_size >= NEED) {
        // fp32 mode with pre-converted bf16 weights in ws
        cvtw_k<<<dim3(2048), dim3(256), 0, stream>>>(
            flag, (const float*)d_in[7], (const float*)d_in[13],
            (const float*)d_in[17], (const float*)d_in[3],
            (const float*)d_in[14], wsW);
        c2g_kernel<0, 1><<<dim3(NBLK), dim3(NTHR), 0, stream>>>(
            flag, cluster, d_in[2], wsW + WS_PREWIH, d_in[5], d_in[6],
            wsW + WS_LINW, d_in[8], d_in[9], d_in[10], d_in[11], d_in[12],
            wsW + WS_DECWIH, d_in[15], wsW + WS_DECWHH, d_in[16],
            wsW + WS_OUTW, d_in[18], d_out);
    } else {
        // fp32 mode, convert weights per-fragment on the fly
        c2g_kernel<1, 1><<<dim3(NBLK), dim3(NTHR), 0, stream>>>(
            flag, cluster, d_in[2], d_in[3], d_in[5], d_in[6], d_in[7], d_in[8],
            d_in[9], d_in[10], d_in[11], d_in[12], d_in[13], d_in[15], d_in[14],
            d_in[16], d_in[17], d_in[18], d_out);
    }
}